// Round 8
// baseline (1157.494 us; speedup 1.0000x reference)
//
#include <hip/hip_runtime.h>
#include <hip/hip_bf16.h>

// AUGRU dynamic RNN: B=1024, T=512, D=128.
// Round-8 = Round-7 with ONE change: __launch_bounds__(512,1).
// R7's 2x regression was register starvation, not the interleave: leftover
// launch_bounds(512,2) capped VGPR at 128 (counter showed exactly 128;
// SGPR 32->112 = spill bookkeeping) while two-group state needs ~220+.
// With (512,1) each wave may use up to 512 unified VGPR/AGPR; 1 block/CU is
// structurally true anyway (32 blocks, 60KB LDS).
// Two-group interleave (unchanged from R7): block owns 32 batch rows = two
// independent 16-row groups A,B, phase-shifted half a step; each barrier
// interval = {one group's MFMA} + {other group's trans/update}. Per-group
// math identical to R6 (587.6us): R5 x-partial pipelining, cvt_pk_bf16,
// folded biases, lgkm-only barriers.

#define Bn 1024
#define Tn 512
#define Dn 128

typedef __attribute__((ext_vector_type(8))) short short8;   // 8 bf16 (4 VGPR)
typedef __attribute__((ext_vector_type(4))) float f32x4;

#define HS 132   // f32 LDS row stride (floats)
#define BS 136   // bf16 LDS row stride (shorts): 272 B = 17*16B

#define NL2E  (-1.4426950408889634f)   // -log2(e)
#define N2L2E (-2.8853900817779268f)   // -2*log2(e)

__device__ __forceinline__ short f2bf(float f) {            // cold paths only
    __hip_bfloat16 h = __float2bfloat16(f);   // RNE
    return __builtin_bit_cast(short, h);
}
__device__ __forceinline__ unsigned cvt_pk_bf16(float a, float b) {
    unsigned r;
    asm("v_cvt_pk_bf16_f32 %0, %1, %2" : "=v"(r) : "v"(a), "v"(b));
    return r;
}
// LDS-only barrier: order LDS ops across waves WITHOUT draining vmcnt.
__device__ __forceinline__ void barrier_lds() {
    __builtin_amdgcn_sched_barrier(0);
    asm volatile("s_waitcnt lgkmcnt(0)" ::: "memory");
    __builtin_amdgcn_s_barrier();
    __builtin_amdgcn_sched_barrier(0);
}

#define MFMA_(a, b, c) __builtin_amdgcn_mfma_f32_16x16x32_bf16((a), (b), (c), 0, 0, 0)

__launch_bounds__(512, 1)
__global__ void augru_kernel(const float* __restrict__ X,    // [B,T,D]
                             const float* __restrict__ ATT,  // [B,T,1]
                             const float* __restrict__ GK,   // [256,256]
                             const float* __restrict__ GB,   // [256]
                             const float* __restrict__ CK,   // [256,128]
                             const float* __restrict__ CB,   // [128]
                             const int*   __restrict__ SL,   // [B,1]
                             float* __restrict__ OUT) {      // [B,T,D]
    __shared__ short hbA [16 * BS], hbB [16 * BS];   // h bf16 mirrors
    __shared__ short rhbA[16 * BS], rhbB[16 * BS];   // r*h bf16
    __shared__ short xbA [16 * BS], xbB [16 * BS];   // x tile (single buf)
    __shared__ float hfA [16 * HS], hfB [16 * HS];   // master h f32
    __shared__ float ubA [16 * HS], ubB [16 * HS];   // u' f32
    __shared__ float abufA[2][16], abufB[2][16];
    __shared__ int   lenbufA[16], lenbufB[16];

    const int tid  = threadIdx.x;
    const int wid  = tid >> 6;          // 0..7
    const int lane = tid & 63;
    const int lm   = lane & 15;
    const int q    = lane >> 4;
    const int b0A  = blockIdx.x * 32;
    const int b0B  = b0A + 16;

    // ---------- preload weight B-frags (shared by both groups) ----------
    short8 fgx[2][4], fgh[2][4], fcx[4], fch[4];
    const int gcolb = 32 * wid + lm;
    const int ccol  = 16 * wid + lm;
#pragma unroll
    for (int ns = 0; ns < 2; ++ns) {
        const int col = gcolb + 16 * ns;
#pragma unroll
        for (int ks = 0; ks < 4; ++ks) {
            short8 vx, vh;
#pragma unroll
            for (int j = 0; j < 8; ++j) {
                const int k = ks * 32 + q * 8 + j;
                vx[j] = f2bf(GK[k * 256 + col]);
                vh[j] = f2bf(GK[(128 + k) * 256 + col]);
            }
            fgx[ns][ks] = vx; fgh[ns][ks] = vh;
        }
    }
#pragma unroll
    for (int ks = 0; ks < 4; ++ks) {
        short8 vx, vh;
#pragma unroll
        for (int j = 0; j < 8; ++j) {
            const int k = ks * 32 + q * 8 + j;
            vx[j] = f2bf(CK[k * 128 + ccol]);
            vh[j] = f2bf(CK[(128 + k) * 128 + ccol]);
        }
        fcx[ks] = vx; fch[ks] = vh;
    }
    const float pb0 = GB[gcolb]      * NL2E;
    const float pb1 = GB[gcolb + 16] * NL2E;
    const float cbp = CB[ccol]       * N2L2E;

    // ---------- init LDS ----------
    for (int i = tid; i < 16 * HS; i += 512) { hfA[i] = 0.0f; hfB[i] = 0.0f; }
    for (int i = tid; i < 16 * BS; i += 512) { hbA[i] = 0;    hbB[i] = 0;    }
    if (tid < 16) {
        lenbufA[tid]  = SL[b0A + tid];
        lenbufB[tid]  = SL[b0B + tid];
        abufA[0][tid] = ATT[(size_t)(b0A + tid) * Tn];
        abufB[0][tid] = ATT[(size_t)(b0B + tid) * Tn];
    }
    const int prow = tid >> 5;
    const int pcol = (tid & 31) * 4;

#define STAGE_X(XBg, B0g, tt) {                                                     \
        float4 v_ = *(const float4*)(X + ((size_t)((B0g) + prow) * Tn + (tt)) * Dn + pcol); \
        uint2 pp_; pp_.x = cvt_pk_bf16(v_.x, v_.y); pp_.y = cvt_pk_bf16(v_.z, v_.w); \
        *(uint2*)&XBg[prow * BS + pcol] = pp_; }

    STAGE_X(xbA, b0A, 0)
    STAGE_X(xbB, b0B, 0)
    __syncthreads();

    int lenA_i[4], lenB_i[4];
#pragma unroll
    for (int i = 0; i < 4; ++i) { lenA_i[i] = lenbufA[q * 4 + i]; lenB_i[i] = lenbufB[q * 4 + i]; }

    // ---------- prologue: x-partials for step 0 (both groups) ----------
    f32x4 gxA0 = {0,0,0,0}, gxA1 = {0,0,0,0}, cxA = {0,0,0,0};
    f32x4 gxB0 = {0,0,0,0}, gxB1 = {0,0,0,0}, cxB = {0,0,0,0};
    f32x4 ccA, ccB, g0A, g1A, g0B, g1B;
    float4 xpreA, xpreB; float apreA, apreB;
    {
        short8 fa[4], fb[4];
#pragma unroll
        for (int ks = 0; ks < 4; ++ks) {
            fa[ks] = *(const short8*)&xbA[lm * BS + ks * 32 + q * 8];
            fb[ks] = *(const short8*)&xbB[lm * BS + ks * 32 + q * 8];
        }
#pragma unroll
        for (int ks = 0; ks < 4; ++ks) {
            gxA0 = MFMA_(fa[ks], fgx[0][ks], gxA0);
            gxA1 = MFMA_(fa[ks], fgx[1][ks], gxA1);
            cxA  = MFMA_(fa[ks], fcx[ks],  cxA);
            gxB0 = MFMA_(fb[ks], fgx[0][ks], gxB0);
            gxB1 = MFMA_(fb[ks], fgx[1][ks], gxB1);
            cxB  = MFMA_(fb[ks], fcx[ks],  cxB);
        }
    }
    __syncthreads();
    STAGE_X(xbA, b0A, 1)
    STAGE_X(xbB, b0B, 1)
    __syncthreads();

    // ---------- phase macros (each group's math identical to R6) ----------
#define P1MFMA(HBg, XBg, GX0, GX1, CXg, CCg, G0, G1, XPREg, APREg, B0g, t)          \
    {                                                                               \
        const int tp1 = ((t) + 1 < Tn) ? (t) + 1 : Tn - 1;                          \
        const int tp2 = ((t) + 2 < Tn) ? (t) + 2 : Tn - 1;                          \
        XPREg = *(const float4*)(X + ((size_t)((B0g) + prow) * Tn + tp2) * Dn + pcol); \
        APREg = (tid < 16) ? ATT[(size_t)((B0g) + tid) * Tn + tp1] : 0.0f;          \
        short8 axn[4], ah[4];                                                       \
        _Pragma("unroll")                                                           \
        for (int ks = 0; ks < 4; ++ks) {                                            \
            axn[ks] = *(const short8*)&XBg[lm * BS + ks * 32 + q * 8];              \
            ah[ks]  = *(const short8*)&HBg[lm * BS + ks * 32 + q * 8];              \
        }                                                                           \
        G0 = GX0; G1 = GX1; CCg = CXg;                                              \
        f32x4 n0 = {0,0,0,0}, n1 = {0,0,0,0}, n2 = {0,0,0,0};                       \
        _Pragma("unroll")                                                           \
        for (int ks = 0; ks < 4; ++ks) {                                            \
            G0 = MFMA_(ah[ks], fgh[0][ks], G0);                                     \
            G1 = MFMA_(ah[ks], fgh[1][ks], G1);                                     \
            n0 = MFMA_(axn[ks], fgx[0][ks], n0);                                    \
            n1 = MFMA_(axn[ks], fgx[1][ks], n1);                                    \
            n2 = MFMA_(axn[ks], fcx[ks],  n2);                                      \
        }                                                                           \
        GX0 = n0; GX1 = n1; CXg = n2;                                               \
    }

#define ACT(RHBg, UBg, HFg, ABUFg, G0, G1, t)                                       \
    {                                                                               \
        if (wid < 4) {            /* r cols */                                      \
            const int col0 = 32 * wid + lm;                                         \
            _Pragma("unroll")                                                       \
            for (int i = 0; i < 4; ++i) {                                           \
                const int row = q * 4 + i;                                          \
                const float e0 = __builtin_amdgcn_exp2f(fmaf(G0[i], NL2E, pb0));    \
                const float e1 = __builtin_amdgcn_exp2f(fmaf(G1[i], NL2E, pb1));    \
                const float rh0 = __builtin_amdgcn_rcpf(1.0f + e0) * HFg[row * HS + col0];      \
                const float rh1 = __builtin_amdgcn_rcpf(1.0f + e1) * HFg[row * HS + col0 + 16]; \
                const unsigned p = cvt_pk_bf16(rh0, rh1);                           \
                RHBg[row * BS + col0]      = (short)p;                              \
                RHBg[row * BS + col0 + 16] = (short)(p >> 16);                      \
            }                                                                       \
        } else {                  /* u cols */                                      \
            const int cu0 = 32 * (wid - 4) + lm;                                    \
            float am[4];                                                            \
            _Pragma("unroll")                                                       \
            for (int i = 0; i < 4; ++i) am[i] = 1.0f - ABUFg[(t) & 1][q * 4 + i];   \
            _Pragma("unroll")                                                       \
            for (int i = 0; i < 4; ++i) {                                           \
                const int row = q * 4 + i;                                          \
                const float e0 = __builtin_amdgcn_exp2f(fmaf(G0[i], NL2E, pb0));    \
                const float e1 = __builtin_amdgcn_exp2f(fmaf(G1[i], NL2E, pb1));    \
                UBg[row * HS + cu0]      = am[i] * __builtin_amdgcn_rcpf(1.0f + e0); \
                UBg[row * HS + cu0 + 16] = am[i] * __builtin_amdgcn_rcpf(1.0f + e1); \
            }                                                                       \
        }                                                                           \
    }

#define P2MFMA(RHBg, CCg)                                                           \
    {                                                                               \
        _Pragma("unroll")                                                           \
        for (int ks = 0; ks < 4; ++ks) {                                            \
            short8 arh = *(const short8*)&RHBg[lm * BS + ks * 32 + q * 8];          \
            CCg = MFMA_(arh, fch[ks], CCg);                                         \
        }                                                                           \
    }

#define UPD(HBg, XBg, HFg, UBg, ABUFg, LEN, CCg, XPREg, APREg, B0g, t)              \
    {                                                                               \
        float hxv[4];                                                               \
        _Pragma("unroll")                                                           \
        for (int i = 0; i < 4; ++i) {                                               \
            const int row = q * 4 + i;                                              \
            const float e  = __builtin_amdgcn_exp2f(fmaf(CCg[i], N2L2E, cbp));      \
            const float cv = fmaf(2.0f, __builtin_amdgcn_rcpf(1.0f + e), -1.0f);    \
            const float up   = UBg[row * HS + ccol];                                \
            const float hold = HFg[row * HS + ccol];                                \
            const float hn   = fmaf(up, hold - cv, cv);                             \
            const bool valid = ((t) < LEN[i]);                                      \
            const float hnext = valid ? hn : hold;                                  \
            OUT[((size_t)((B0g) + row) * Tn + (t)) * Dn + ccol] = valid ? hn : 0.0f; \
            HFg[row * HS + ccol] = hnext;                                           \
            hxv[i] = hnext;                                                         \
        }                                                                           \
        {                                                                           \
            const unsigned pA_ = cvt_pk_bf16(hxv[0], hxv[1]);                       \
            const unsigned pB_ = cvt_pk_bf16(hxv[2], hxv[3]);                       \
            HBg[(q * 4 + 0) * BS + ccol] = (short)pA_;                              \
            HBg[(q * 4 + 1) * BS + ccol] = (short)(pA_ >> 16);                      \
            HBg[(q * 4 + 2) * BS + ccol] = (short)pB_;                              \
            HBg[(q * 4 + 3) * BS + ccol] = (short)(pB_ >> 16);                      \
        }                                                                           \
        {                                                                           \
            uint2 pp_;                                                              \
            pp_.x = cvt_pk_bf16(XPREg.x, XPREg.y);                                  \
            pp_.y = cvt_pk_bf16(XPREg.z, XPREg.w);                                  \
            *(uint2*)&XBg[prow * BS + pcol] = pp_;                                  \
            if (tid < 16) ABUFg[((t) + 1) & 1][tid] = APREg;                        \
        }                                                                           \
    }

    // ---------- B head-start: PH1 of step 0 ----------
    P1MFMA(hbB, xbB, gxB0, gxB1, cxB, ccB, g0B, g1B, xpreB, apreB, b0B, 0)
    ACT(rhbB, ubB, hfB, abufB, g0B, g1B, 0)
    barrier_lds();

    // ---------- time loop: iter t does A-step t and B-steps t/t+1 halves ----
    for (int t = 0; t < Tn; ++t) {
        // interval 1: A.PH1(t)  ||  B.PH2(t)
        P1MFMA(hbA, xbA, gxA0, gxA1, cxA, ccA, g0A, g1A, xpreA, apreA, b0A, t)
        P2MFMA(rhbB, ccB)
        ACT(rhbA, ubA, hfA, abufA, g0A, g1A, t)
        UPD(hbB, xbB, hfB, ubB, abufB, lenB_i, ccB, xpreB, apreB, b0B, t)
        barrier_lds();
        // interval 2: A.PH2(t)  ||  B.PH1(t+1)
        P2MFMA(rhbA, ccA)
        P1MFMA(hbB, xbB, gxB0, gxB1, cxB, ccB, g0B, g1B, xpreB, apreB, b0B, t + 1)
        UPD(hbA, xbA, hfA, ubA, abufA, lenA_i, ccA, xpreA, apreA, b0A, t)
        ACT(rhbB, ubB, hfB, abufB, g0B, g1B, t + 1)
        barrier_lds();
    }
#undef P1MFMA
#undef ACT
#undef P2MFMA
#undef UPD
#undef STAGE_X
}

extern "C" void kernel_launch(void* const* d_in, const int* in_sizes, int n_in,
                              void* d_out, int out_size, void* d_ws, size_t ws_size,
                              hipStream_t stream) {
    (void)in_sizes; (void)n_in; (void)d_ws; (void)ws_size; (void)out_size;
    const float* X   = (const float*)d_in[0];
    const float* ATT = (const float*)d_in[1];
    const float* GK  = (const float*)d_in[2];
    const float* GB  = (const float*)d_in[3];
    const float* CK  = (const float*)d_in[4];
    const float* CB  = (const float*)d_in[5];
    const int*   SL  = (const int*)d_in[6];
    float* OUT = (float*)d_out;

    augru_kernel<<<dim3(Bn / 32), dim3(512), 0, stream>>>(X, ATT, GK, GB, CK, CB, SL, OUT);
}

// Round 9
// 525.826 us; speedup vs baseline: 2.2013x; 2.2013x over previous
//
#include <hip/hip_runtime.h>
#include <hip/hip_bf16.h>

// AUGRU dynamic RNN: B=1024, T=512, D=128.
// 64 blocks x 512 threads (8 waves); block owns 16 batch rows for all T.
// Base = R6 (587.6us). Round-9 change: COLUMN-ALIGNED GATE MAPPING deletes
// the hf/ub LDS arrays. Wave w's two gate MFMA col-groups are {ccol,
// 128+ccol} (ccol = 16w+lm) instead of {32w+lm, 32w+16+lm}: the r and u
// gates for col ccol are produced in the SAME lane that owns h[.][ccol], so
// master h lives in registers (h_reg[4] f32), u' = (1-a)*u stays in
// registers, r*h uses register h. Removes ~128 small DS ops/CU-step (~600
// cyc of the ~2690-cyc LDS-pipe floor — the kernel is LDS-pipe-bound:
// R8's exact-2x at half the CUs + R6 LDS accounting == step time).
// Kept from ladder: R5 cross-step x-partials, cvt_pk_bf16, folded biases,
// lgkm-only barriers, 2 barriers/step, 64 blocks.

#define Bn 1024
#define Tn 512
#define Dn 128

typedef __attribute__((ext_vector_type(8))) short short8;   // 8 bf16 (4 VGPR)
typedef __attribute__((ext_vector_type(4))) float f32x4;

#define BS 136   // bf16 LDS row stride (shorts): 272 B = 17*16B

#define NL2E  (-1.4426950408889634f)   // -log2(e)
#define N2L2E (-2.8853900817779268f)   // -2*log2(e)

__device__ __forceinline__ short f2bf(float f) {            // cold paths only
    __hip_bfloat16 h = __float2bfloat16(f);   // RNE
    return __builtin_bit_cast(short, h);
}
__device__ __forceinline__ unsigned cvt_pk_bf16(float a, float b) {
    unsigned r;
    asm("v_cvt_pk_bf16_f32 %0, %1, %2" : "=v"(r) : "v"(a), "v"(b));
    return r;
}
// LDS-only barrier: order LDS ops across waves WITHOUT draining vmcnt.
__device__ __forceinline__ void barrier_lds() {
    __builtin_amdgcn_sched_barrier(0);
    asm volatile("s_waitcnt lgkmcnt(0)" ::: "memory");
    __builtin_amdgcn_s_barrier();
    __builtin_amdgcn_sched_barrier(0);
}

#define MFMA_(a, b, c) __builtin_amdgcn_mfma_f32_16x16x32_bf16((a), (b), (c), 0, 0, 0)

__launch_bounds__(512, 1)
__global__ void augru_kernel(const float* __restrict__ X,    // [B,T,D]
                             const float* __restrict__ ATT,  // [B,T,1]
                             const float* __restrict__ GK,   // [256,256]
                             const float* __restrict__ GB,   // [256]
                             const float* __restrict__ CK,   // [256,128]
                             const float* __restrict__ CB,   // [128]
                             const int*   __restrict__ SL,   // [B,1]
                             float* __restrict__ OUT) {      // [B,T,D]
    __shared__ short hb [16 * BS];      // h  (bf16 mirror, A-frag source)
    __shared__ short rhb[16 * BS];      // r*h (bf16, A-frag source)
    __shared__ short xb [2][16 * BS];   // x tile; slot s&1 holds x(s)
    __shared__ float abuf[2][16];
    __shared__ int   lenbuf[16];

    const int tid  = threadIdx.x;
    const int wid  = tid >> 6;          // 0..7
    const int lane = tid & 63;
    const int lm   = lane & 15;
    const int q    = lane >> 4;
    const int b0   = blockIdx.x * 16;
    const int ccol = 16 * wid + lm;     // wave's owned column (r / u-128 / cand / h)

    // ---------- preload weight B-frags (B[k][n]: n=lane&15, k=q*8+j) ----------
    // gate group 0 -> col ccol (r); gate group 1 -> col 128+ccol (u).
    short8 fgx0[4], fgx1[4], fgh0[4], fgh1[4], fcx[4], fch[4];
#pragma unroll
    for (int ks = 0; ks < 4; ++ks) {
        short8 v0, v1, v2, v3, v4, v5;
#pragma unroll
        for (int j = 0; j < 8; ++j) {
            const int k = ks * 32 + q * 8 + j;
            v0[j] = f2bf(GK[k * 256 + ccol]);               // x-part, r col
            v1[j] = f2bf(GK[k * 256 + 128 + ccol]);         // x-part, u col
            v2[j] = f2bf(GK[(128 + k) * 256 + ccol]);       // h-part, r col
            v3[j] = f2bf(GK[(128 + k) * 256 + 128 + ccol]); // h-part, u col
            v4[j] = f2bf(CK[k * 128 + ccol]);               // cand x-part
            v5[j] = f2bf(CK[(128 + k) * 128 + ccol]);       // cand rh-part
        }
        fgx0[ks] = v0; fgx1[ks] = v1; fgh0[ks] = v2; fgh1[ks] = v3;
        fcx[ks] = v4;  fch[ks] = v5;
    }
    const float pb0 = GB[ccol]       * NL2E;
    const float pb1 = GB[128 + ccol] * NL2E;
    const float cbp = CB[ccol]       * N2L2E;

    // ---------- init LDS ----------
    for (int i = tid; i < 16 * BS; i += 512) hb[i] = 0;
    if (tid < 16) {
        lenbuf[tid]  = SL[b0 + tid];
        abuf[0][tid] = ATT[(size_t)(b0 + tid) * Tn];
    }
    const int prow = tid >> 5;            // x staging: row 0..15
    const int pcol = (tid & 31) * 4;      // 4 consecutive floats
    {   // stage x(0) into xb[0]
        float4 v = *(const float4*)(X + ((size_t)(b0 + prow) * Tn + 0) * Dn + pcol);
        uint2 pp; pp.x = cvt_pk_bf16(v.x, v.y); pp.y = cvt_pk_bf16(v.z, v.w);
        *(uint2*)&xb[0][prow * BS + pcol] = pp;
    }
    __syncthreads();

    int len_i[4];
    float h_reg[4] = {0.f, 0.f, 0.f, 0.f};   // master h: rows q*4+i, col ccol
#pragma unroll
    for (int i = 0; i < 4; ++i) len_i[i] = lenbuf[q * 4 + i];

    // ---------- prologue: x-partials for t=0; stage x(1) ----------
    f32x4 gxA0 = {0,0,0,0}, gxA1 = {0,0,0,0}, cxA = {0,0,0,0};
    f32x4 gxB0, gxB1, cxB;
    {
        short8 ax0[4];
#pragma unroll
        for (int ks = 0; ks < 4; ++ks)
            ax0[ks] = *(const short8*)&xb[0][lm * BS + ks * 32 + q * 8];
#pragma unroll
        for (int ks = 0; ks < 4; ++ks) {
            gxA0 = MFMA_(ax0[ks], fgx0[ks], gxA0);
            gxA1 = MFMA_(ax0[ks], fgx1[ks], gxA1);
            cxA  = MFMA_(ax0[ks], fcx[ks],  cxA);
        }
        float4 v = *(const float4*)(X + ((size_t)(b0 + prow) * Tn + 1) * Dn + pcol);
        uint2 pp; pp.x = cvt_pk_bf16(v.x, v.y); pp.y = cvt_pk_bf16(v.z, v.w);
        *(uint2*)&xb[1][prow * BS + pcol] = pp;
    }
    __syncthreads();

#define STEP_BODY(t, GIN0, GIN1, CIN, GOUT0, GOUT1, COUT)                         \
    {                                                                             \
        const int cur = (t) & 1, nxt = cur ^ 1;                                   \
        const int tp1 = ((t) + 1 < Tn) ? (t) + 1 : Tn - 1;                        \
        const int tp2 = ((t) + 2 < Tn) ? (t) + 2 : Tn - 1;                        \
        float4 xpre = *(const float4*)(X + ((size_t)(b0 + prow) * Tn + tp2) * Dn + pcol); \
        float  apre = (tid < 16) ? ATT[(size_t)(b0 + tid) * Tn + tp1] : 0.0f;     \
        /* A-frags: h(t) from hb, x(t+1) from xb[nxt] */                          \
        short8 axn[4], ah[4];                                                     \
        _Pragma("unroll")                                                         \
        for (int ks = 0; ks < 4; ++ks) {                                          \
            axn[ks] = *(const short8*)&xb[nxt][lm * BS + ks * 32 + q * 8];        \
            ah[ks]  = *(const short8*)&hb[lm * BS + ks * 32 + q * 8];             \
        }                                                                         \
        /* P1: gate = saved x-partial + h-part (4-deep); next x-partials float */ \
        f32x4 g0 = GIN0, g1 = GIN1;                                               \
        f32x4 n0 = {0,0,0,0}, n1 = {0,0,0,0}, n2 = {0,0,0,0};                     \
        _Pragma("unroll")                                                         \
        for (int ks = 0; ks < 4; ++ks) {                                          \
            g0 = MFMA_(ah[ks], fgh0[ks], g0);                                     \
            g1 = MFMA_(ah[ks], fgh1[ks], g1);                                     \
        }                                                                         \
        _Pragma("unroll")                                                         \
        for (int ks = 0; ks < 4; ++ks) {                                          \
            n0 = MFMA_(axn[ks], fgx0[ks], n0);                                    \
            n1 = MFMA_(axn[ks], fgx1[ks], n1);                                    \
            n2 = MFMA_(axn[ks], fcx[ks],  n2);                                    \
        }                                                                         \
        /* activations: wave-uniform; r,u for col ccol in the owning lane */      \
        float am[4], up[4], rhv[4];                                               \
        _Pragma("unroll")                                                         \
        for (int i = 0; i < 4; ++i) am[i] = 1.0f - abuf[cur][q * 4 + i];          \
        _Pragma("unroll")                                                         \
        for (int i = 0; i < 4; ++i) {                                             \
            const float e0 = __builtin_amdgcn_exp2f(fmaf(g0[i], NL2E, pb0));      \
            rhv[i] = __builtin_amdgcn_rcpf(1.0f + e0) * h_reg[i];                 \
            const float e1 = __builtin_amdgcn_exp2f(fmaf(g1[i], NL2E, pb1));      \
            up[i] = am[i] * __builtin_amdgcn_rcpf(1.0f + e1);                     \
        }                                                                         \
        {                                                                         \
            const unsigned pA_ = cvt_pk_bf16(rhv[0], rhv[1]);                     \
            const unsigned pB_ = cvt_pk_bf16(rhv[2], rhv[3]);                     \
            rhb[(q * 4 + 0) * BS + ccol] = (short)pA_;                            \
            rhb[(q * 4 + 1) * BS + ccol] = (short)(pA_ >> 16);                    \
            rhb[(q * 4 + 2) * BS + ccol] = (short)pB_;                            \
            rhb[(q * 4 + 3) * BS + ccol] = (short)(pB_ >> 16);                    \
        }                                                                         \
        barrier_lds();                                                            \
        /* P2: cand = saved x-partial + rh-part (4-deep) */                       \
        f32x4 cc = CIN;                                                           \
        _Pragma("unroll")                                                         \
        for (int ks = 0; ks < 4; ++ks) {                                          \
            short8 arh = *(const short8*)&rhb[lm * BS + ks * 32 + q * 8];         \
            cc = MFMA_(arh, fch[ks], cc);                                         \
        }                                                                         \
        /* h update + output (all state register-resident) */                     \
        float hxv[4];                                                             \
        _Pragma("unroll")                                                         \
        for (int i = 0; i < 4; ++i) {                                             \
            const int row = q * 4 + i;                                            \
            const float e  = __builtin_amdgcn_exp2f(fmaf(cc[i], N2L2E, cbp));     \
            const float cv = fmaf(2.0f, __builtin_amdgcn_rcpf(1.0f + e), -1.0f);  \
            const float hn = fmaf(up[i], h_reg[i] - cv, cv);                      \
            const bool valid = ((t) < len_i[i]);                                  \
            const float hnext = valid ? hn : h_reg[i];                            \
            OUT[((size_t)(b0 + row) * Tn + (t)) * Dn + ccol] = valid ? hn : 0.0f; \
            h_reg[i] = hnext;                                                     \
            hxv[i] = hnext;                                                       \
        }                                                                         \
        {                                                                         \
            const unsigned pA_ = cvt_pk_bf16(hxv[0], hxv[1]);                     \
            const unsigned pB_ = cvt_pk_bf16(hxv[2], hxv[3]);                     \
            hb[(q * 4 + 0) * BS + ccol] = (short)pA_;                             \
            hb[(q * 4 + 1) * BS + ccol] = (short)(pA_ >> 16);                     \
            hb[(q * 4 + 2) * BS + ccol] = (short)pB_;                             \
            hb[(q * 4 + 3) * BS + ccol] = (short)(pB_ >> 16);                     \
        }                                                                         \
        /* stage x(t+2) into xb[cur]; a(t+1) into abuf[nxt] */                    \
        {                                                                         \
            uint2 pp_;                                                            \
            pp_.x = cvt_pk_bf16(xpre.x, xpre.y);                                  \
            pp_.y = cvt_pk_bf16(xpre.z, xpre.w);                                  \
            *(uint2*)&xb[cur][prow * BS + pcol] = pp_;                            \
            if (tid < 16) abuf[nxt][tid] = apre;                                  \
        }                                                                         \
        barrier_lds();                                                            \
        GOUT0 = n0; GOUT1 = n1; COUT = n2;                                        \
    }

    // ---------- time loop (unrolled x2: static A/B partial-sum sets) ----------
    for (int t = 0; t < Tn; t += 2) {
        STEP_BODY(t,     gxA0, gxA1, cxA, gxB0, gxB1, cxB)
        STEP_BODY(t + 1, gxB0, gxB1, cxB, gxA0, gxA1, cxA)
    }
#undef STEP_BODY
}

extern "C" void kernel_launch(void* const* d_in, const int* in_sizes, int n_in,
                              void* d_out, int out_size, void* d_ws, size_t ws_size,
                              hipStream_t stream) {
    (void)in_sizes; (void)n_in; (void)d_ws; (void)ws_size; (void)out_size;
    const float* X   = (const float*)d_in[0];
    const float* ATT = (const float*)d_in[1];
    const float* GK  = (const float*)d_in[2];
    const float* GB  = (const float*)d_in[3];
    const float* CK  = (const float*)d_in[4];
    const float* CB  = (const float*)d_in[5];
    const int*   SL  = (const int*)d_in[6];
    float* OUT = (float*)d_out;

    augru_kernel<<<dim3(Bn / 16), dim3(512), 0, stream>>>(X, ATT, GK, GB, CK, CB, SL, OUT);
}